// Round 4
// baseline (312.460 us; speedup 1.0000x reference)
//
#include <hip/hip_runtime.h>
#include <math.h>

// Problem constants
#define B_    32
#define C3_   1024
#define C4_   2048
#define C_    3072
#define P_    784      // 28*28
#define Q_    196      // 14*14
#define L_    9
#define NG_   25088    // B_*P_
#define A_    312
#define NC_   200

// d_out layout (floats): attr(32x312), class(32x200), maps(32x9x784), af(32x3072x9)
#define ATTR_OFF  0
#define CLASS_OFF 9984
#define MAPS_OFF  16384
#define AF_OFF    242176

// workspace layout (floats)
#define ASQ_OFF   0
#define MF_OFF    16
#define LOGITS_OFF 98320                          // 9 x NG_ = 225792 floats
#define Y_OFF     (LOGITS_OFF + 9 * NG_)          // 32 x 9 x 196 = 56448
#define MP_OFF    (Y_OFF + 32 * 9 * Q_)           // 32 x 9 x 196
// end: ~380k floats = 1.5 MB (part3/paf/y4p eliminated by atomic accumulation)

typedef __attribute__((ext_vector_type(8))) short bf16x8;
typedef __attribute__((ext_vector_type(4))) float f32x4;

__device__ __forceinline__ short f2bf(float f) {
    union { float f; unsigned u; } v; v.f = f;
    unsigned r = v.u + 0x7FFFu + ((v.u >> 16) & 1u);   // RNE
    return (short)(r >> 16);
}

// async global->LDS, 16B per lane, LDS dest = uniform base + lane*16
#define GLDS16(gp, lp) __builtin_amdgcn_global_load_lds(                    \
        (const __attribute__((address_space(1))) unsigned int*)(gp),        \
        (__attribute__((address_space(3))) unsigned int*)(lp), 16, 0, 0)

// ====================== zK: zero Y+logits accumulators; block 0 computes a_sq
__global__ __launch_bounds__(256) void zK(const float* __restrict__ conv_w,
                                          float* __restrict__ Y,
                                          float* __restrict__ logits,
                                          float* __restrict__ asq) {
    if (blockIdx.x == 0) {
        __shared__ float red[256];
        int t = threadIdx.x;
        for (int l = 0; l < L_; ++l) {
            float s = 0.f;
            for (int c = t; c < C_; c += 256) s += conv_w[l * C_ + c];
            red[t] = s; __syncthreads();
            for (int o = 128; o > 0; o >>= 1) {
                if (t < o) red[t] += red[t + o];
                __syncthreads();
            }
            if (t == 0) asq[l] = red[0];
            __syncthreads();
        }
        return;
    }
    int i = (blockIdx.x - 1) * 256 + threadIdx.x;
    if (i < 32 * 9 * Q_) Y[i] = 0.f;
    else if (i < 32 * 9 * Q_ + 9 * NG_) logits[i - 32 * 9 * Q_] = 0.f;
}

// ============================================================= K_A (fused)
// Rounds 0-3: three different staging engines all land at ~67-70us (empirical
// plateau; HBM 19%, VALU 12%, occupancy-invariant). Keep the round-3 chunked
// GLDS pipeline; only the epilogue changes: device-scope f32 atomics
// accumulate straight into logits (l3, pre-scaled by 2) and Y (l4), deleting
// the part3/y4p roundtrips (-43 MB traffic) and the kB reduce kernel.
//   blocks [0,1568): l3.  slab = bid/98 (16 slabs of 64 ch),
//                    g-tile = bid%98 (256 consecutive g = b*784+px).
//   blocks [1568,2592): l4. b = idx>>5, grp = idx&31; row = 196 px (+pad).
__global__ __launch_bounds__(256, 5) void kA(
        const float* __restrict__ l3, const float* __restrict__ l4,
        const float* __restrict__ conv_w,
        float* __restrict__ logits, float* __restrict__ Y) {
    __shared__ float X[2][16 * 256];   // 32768 B -> 5 blocks/CU
    int bid = blockIdx.x;
    int t = threadIdx.x;
    int wave = t >> 6, lane = t & 63;

    bool isl3 = (bid < 1568);
    int slab = 0, g0 = 0, b = 0, grp = 0, cbase_w;
    const float* gbase;     // per-lane base address for channel-row 0
    size_t rowpitch;
    if (isl3) {
        slab = bid / 98;                 // block-uniform
        g0 = (bid % 98) * 256;
        int gidx = g0 + lane * 4;        // 4 floats (16B) per lane
        int bb = gidx / 784, px = gidx % 784;   // 4 | 784 -> no group split
        gbase = l3 + ((size_t)bb * C3_ + slab * 64) * P_ + px;
        rowpitch = P_;
        cbase_w = C4_ + slab * 64;
    } else {
        int idx = bid - 1568;
        b = idx >> 5; grp = idx & 31;    // block-uniform
        int q = lane * 4;
        if (q > 192) q = 192;            // lanes 49..63: dup same 16B (1 line)
        gbase = l4 + ((size_t)b * C4_ + grp * 64) * Q_ + q;
        rowpitch = Q_;
        cbase_w = grp * 64;
    }

    // prologue: chunk 0 -> buf 0 (wave w stages in-chunk rows w*4..w*4+3)
#pragma unroll
    for (int r = 0; r < 4; ++r) {
        int row = wave * 4 + r;
        GLDS16(gbase + (size_t)row * rowpitch, &X[0][row * 256]);
    }

    float acc[9];
#pragma unroll
    for (int l = 0; l < 9; ++l) acc[l] = 0.f;

#pragma unroll
    for (int j = 0; j < 4; ++j) {
        const int cur = j & 1;
        if (j < 3) {
#pragma unroll
            for (int r = 0; r < 4; ++r) {
                int row = wave * 4 + r;           // in-chunk row
                int ch = (j + 1) * 16 + row;      // global channel row
                GLDS16(gbase + (size_t)ch * rowpitch, &X[cur ^ 1][row * 256]);
            }
            // counted wait: own chunk-j loads (oldest 4) done; chunk j+1's
            // 4 loads stay in flight across the barrier.
            asm volatile("s_waitcnt vmcnt(4)" ::: "memory");
        } else {
            asm volatile("s_waitcnt vmcnt(0)" ::: "memory");
        }
        __builtin_amdgcn_s_barrier();      // all waves' chunk-j rows in LDS

        if (isl3 || t < 196) {
#pragma unroll
            for (int c = 0; c < 16; ++c) {
                float x = X[cur][c * 256 + t];
#pragma unroll
                for (int l = 0; l < 9; ++l)
                    acc[l] = fmaf(conv_w[(size_t)l * C_ + cbase_w + j * 16 + c],
                                  x, acc[l]);
            }
        }
        __builtin_amdgcn_s_barrier();      // reads done before buf reuse
    }

    if (isl3) {
#pragma unroll
        for (int l = 0; l < 9; ++l)
            atomicAdd(&logits[(size_t)l * NG_ + g0 + t], 2.f * acc[l]);
    } else if (t < 196) {
#pragma unroll
        for (int l = 0; l < 9; ++l)
            atomicAdd(&Y[((size_t)b * 9 + l) * Q_ + t], acc[l]);
    }
}

// ====== K_C: maps = softmax_l( logits_accum + 2*upsample(Y) - asq )  (fused)
__global__ __launch_bounds__(256) void kC(const float* __restrict__ logits,
                                          const float* __restrict__ Y,
                                          const float* __restrict__ asq,
                                          float* __restrict__ out_maps) {
    int g = blockIdx.x * 256 + threadIdx.x;   // 98 blocks, exact fit
    int b = g / P_, p = g % P_;
    int yy = p / 28, xx = p % 28;
    float sy = 0.5f * yy - 0.25f, sx = 0.5f * xx - 0.25f;
    float fyf = floorf(sy), fxf = floorf(sx);
    float fy = sy - fyf, fx = sx - fxf;
    int ya = max(0, (int)fyf), yb = min(13, (int)fyf + 1);
    int xa = max(0, (int)fxf), xb = min(13, (int)fxf + 1);
    float w00 = (1.f - fy) * (1.f - fx), w01 = (1.f - fy) * fx;
    float w10 = fy * (1.f - fx),         w11 = fy * fx;
    float v[9];
#pragma unroll
    for (int l = 0; l < 9; ++l) {
        const float* Yl = Y + ((size_t)b * 9 + l) * Q_;
        float ab4 = w00 * Yl[ya * 14 + xa] + w01 * Yl[ya * 14 + xb]
                  + w10 * Yl[yb * 14 + xa] + w11 * Yl[yb * 14 + xb];
        v[l] = logits[(size_t)l * NG_ + g] + 2.f * ab4 - asq[l];
    }
    float m = v[0];
#pragma unroll
    for (int l = 1; l < 9; ++l) m = fmaxf(m, v[l]);
    float sum = 0.f;
#pragma unroll
    for (int l = 0; l < 9; ++l) { v[l] = expf(v[l] - m); sum += v[l]; }
    float inv = 1.f / sum;
#pragma unroll
    for (int l = 0; l < 9; ++l)
        out_maps[(size_t)b * (L_ * P_) + l * P_ + p] = v[l] * inv;
}

// ============== K_D: adjoint bilinear downsample of maps -> Mp[b,l,q]
__device__ __forceinline__ int adj_taps(int q, int* ys, float* wy) {
    if (q == 0)  { ys[0] = 0;  wy[0] = 1.00f; ys[1] = 1;  wy[1] = 0.75f;
                   ys[2] = 2;  wy[2] = 0.25f; return 3; }
    if (q == 13) { ys[0] = 25; wy[0] = 0.25f; ys[1] = 26; wy[1] = 0.75f;
                   ys[2] = 27; wy[2] = 1.00f; return 3; }
    ys[0] = 2 * q - 1; wy[0] = 0.25f;
    ys[1] = 2 * q;     wy[1] = 0.75f;
    ys[2] = 2 * q + 1; wy[2] = 0.75f;
    ys[3] = 2 * q + 2; wy[3] = 0.25f;
    return 4;
}

__global__ __launch_bounds__(256) void kD(const float* __restrict__ maps,
                                          float* __restrict__ Mp) {
    int tid = blockIdx.x * 256 + threadIdx.x;
    if (tid >= 32 * 9 * Q_) return;
    int b = tid / (9 * Q_);
    int r = tid % (9 * Q_);
    int l = r / Q_, q = r % Q_;
    int qy = q / 14, qx = q % 14;
    int ys[4], xs[4]; float wy[4], wx[4];
    int ny = adj_taps(qy, ys, wy);
    int nx = adj_taps(qx, xs, wx);
    const float* mrow = maps + (size_t)b * (L_ * P_) + l * P_;
    float s = 0.f;
    for (int i = 0; i < ny; ++i) {
        float rs = 0.f;
        for (int j = 0; j < nx; ++j)
            rs = fmaf(wx[j], mrow[ys[i] * 28 + xs[j]], rs);
        s = fmaf(wy[i], rs, s);
    }
    Mp[(size_t)b * (9 * Q_) + r] = s;
}

// ===================== K_E: all_features via LDS-staged MFMA bf16 (full-K)
// blocks [0,512): l3, b=bid>>4, 64-ch group, K=784 in 4 chunks of 196,
//                 double-buffered LDS, acc carried -> writes out_af FINAL.
// blocks [512,1536): l4, b, 32 grps of 64, K=196 (1 chunk) vs Mp.
// Epilogue also computes mf (mean_features) via 16-lane shfl tree -> kMF dead.
// Staging: 13 fully-unrolled guarded independent float4 loads/thread
// (straight-line -> compiler batch-issues; rolled loops got serialized).
#define SA 232     // LDS row stride (bf16 elems)
__global__ __launch_bounds__(256, 2) void kE(
        const float* __restrict__ l3, const float* __restrict__ l4,
        const float* __restrict__ maps, const float* __restrict__ Mp,
        const float* __restrict__ mod,
        float* __restrict__ out_af, float* __restrict__ mf) {
    __shared__ short As[2][64 * SA];   // 59392 B
    __shared__ short Bs[2][16 * SA];   // 14848 B   (74240 total -> 2 blk/CU)
    int bid = blockIdx.x;
    int t = threadIdx.x;
    int wave = t >> 6, lane = t & 63;
    int row16 = lane & 15, quad = lane >> 4;

    bool isl3 = (bid < 512);
    int b, c0, nchunk, cglob0, pitch;
    const float* xsrc; const float* bsrc;
    if (isl3) {
        b = bid >> 4; c0 = (bid & 15) * 64; nchunk = 4;
        xsrc = l3 + ((size_t)b * C3_ + c0) * P_;
        bsrc = maps + (size_t)b * (L_ * P_);
        pitch = P_;
        cglob0 = C4_ + c0;
    } else {
        int idx = bid - 512;
        b = idx >> 5; c0 = (idx & 31) * 64; nchunk = 1;
        xsrc = l4 + ((size_t)b * C4_ + c0) * Q_;
        bsrc = Mp + (size_t)b * (9 * Q_);
        pitch = Q_;
        cglob0 = c0;
    }

    // zero the K-pad (cols 196..231) of both A buffers once; staging never
    // touches these columns, and B staging zero-fills its own pads per chunk.
#pragma unroll
    for (int it = 0; it < 5; ++it) {
        int i = t + it * 256;
        if (i < 1152) {
            int br = i / 9;                // 0..127: buf = br>>6, row = br&63
            int j = 196 + (i % 9) * 4;
            *(ushort4*)(&As[br >> 6][(br & 63) * SA + j]) =
                make_ushort4(0, 0, 0, 0);
        }
    }

    auto stage = [&](int cc, int buf) {
        int koff = cc * 196;
        float4 va[13];
#pragma unroll
        for (int it = 0; it < 13; ++it) {           // batch-issued, 13 deep
            int i = t + it * 256;
            if (i < 3136) {
                int r = i / 49, j = (i % 49) * 4;
                va[it] = *(const float4*)(xsrc + (size_t)r * pitch + koff + j);
            }
        }
        float4 vb[4];
#pragma unroll
        for (int it = 0; it < 4; ++it) {
            int i = t + it * 256;
            if (i < 928) {
                int r = i / 58, j = (i % 58) * 4;
                if (r < 9 && j < 196)
                    vb[it] = *(const float4*)(bsrc + (size_t)r * pitch + koff + j);
                else
                    vb[it] = make_float4(0.f, 0.f, 0.f, 0.f);
            }
        }
#pragma unroll
        for (int it = 0; it < 13; ++it) {
            int i = t + it * 256;
            if (i < 3136) {
                int r = i / 49, j = (i % 49) * 4;
                ushort4 o;
                o.x = (unsigned short)f2bf(va[it].x);
                o.y = (unsigned short)f2bf(va[it].y);
                o.z = (unsigned short)f2bf(va[it].z);
                o.w = (unsigned short)f2bf(va[it].w);
                *(ushort4*)(&As[buf][r * SA + j]) = o;
            }
        }
#pragma unroll
        for (int it = 0; it < 4; ++it) {
            int i = t + it * 256;
            if (i < 928) {
                int r = i / 58, j = (i % 58) * 4;
                ushort4 o;
                o.x = (unsigned short)f2bf(vb[it].x);
                o.y = (unsigned short)f2bf(vb[it].y);
                o.z = (unsigned short)f2bf(vb[it].z);
                o.w = (unsigned short)f2bf(vb[it].w);
                *(ushort4*)(&Bs[buf][r * SA + j]) = o;
            }
        }
    };

    stage(0, 0);
    __syncthreads();

    f32x4 acc = {0.f, 0.f, 0.f, 0.f};
    for (int cc = 0; cc < nchunk; ++cc) {
        int cur = cc & 1;
        if (cc + 1 < nchunk) stage(cc + 1, cur ^ 1);
        const short* arow = &As[cur][(wave * 16 + row16) * SA];
        const short* brow = &Bs[cur][row16 * SA];
#pragma unroll
        for (int k0 = 0; k0 < 224; k0 += 32) {
            bf16x8 a = *(const bf16x8*)(arow + k0 + quad * 8);
            bf16x8 bv = *(const bf16x8*)(brow + k0 + quad * 8);
            acc = __builtin_amdgcn_mfma_f32_16x16x32_bf16(a, bv, acc, 0, 0, 0);
        }
        __syncthreads();   // buf[cur] reads done; buf[cur^1] writes visible
    }

    // ---- epilogue: af (final) + mf ----
    int l = row16;
    int cg = cglob0 + wave * 16 + quad * 4;
    float afv[4];
#pragma unroll
    for (int r = 0; r < 4; ++r) afv[r] = acc[r] * (1.f / 784.f);
    if (l < 9) {
        size_t base = ((size_t)b * C_ + cg) * 9 + l;
#pragma unroll
        for (int r = 0; r < 4; ++r) out_af[base + (size_t)r * 9] = afv[r];
    }
    // mf[b,c] = (sum_{l<8} af[c,l]*mod[c,l]) / 8 ; 9 l-values live in lanes
    // row16=0..8 of each quad-group -> 16-lane xor-tree reduce.
    float term[4];
#pragma unroll
    for (int r = 0; r < 4; ++r)
        term[r] = (l < 8) ? afv[r] * mod[(size_t)(cg + r) * 9 + l] : 0.f;
#pragma unroll
    for (int s = 1; s < 16; s <<= 1)
#pragma unroll
        for (int r = 0; r < 4; ++r) term[r] += __shfl_xor(term[r], s);
    if (row16 == 0) {
#pragma unroll
        for (int r = 0; r < 4; ++r)
            mf[(size_t)b * C_ + cg + r] = term[r] * 0.125f;
    }
}

// -------------------------------------------------- K_F: attr = mf @ attr_w.T
__global__ __launch_bounds__(256) void kF(
        const float* __restrict__ mf, const float* __restrict__ attr_w,
        const float* __restrict__ attr_b, float* __restrict__ out_attr) {
    int idx = blockIdx.x * 4 + (threadIdx.x >> 6);   // idx = b*312 + a
    int lane = threadIdx.x & 63;
    int b = idx / A_, a = idx % A_;
    const float4* wr = (const float4*)(attr_w + (size_t)a * C_);
    const float4* mr = (const float4*)(mf + (size_t)b * C_);
    float acc = 0.f;
    for (int j = lane; j < C_ / 4; j += 64) {
        float4 w = wr[j], m = mr[j];
        acc += w.x * m.x + w.y * m.y + w.z * m.z + w.w * m.w;
    }
    acc += __shfl_xor(acc, 1);  acc += __shfl_xor(acc, 2);
    acc += __shfl_xor(acc, 4);  acc += __shfl_xor(acc, 8);
    acc += __shfl_xor(acc, 16); acc += __shfl_xor(acc, 32);
    if (lane == 0) out_attr[idx] = acc + attr_b[a];
}

// ---------------------------------------------- K_G: class = attr @ class_w.T
__global__ __launch_bounds__(256) void kG(
        const float* __restrict__ attr, const float* __restrict__ class_w,
        float* __restrict__ out_class) {
    int idx = blockIdx.x * 4 + (threadIdx.x >> 6);   // idx = b*200 + n
    int lane = threadIdx.x & 63;
    int b = idx / NC_, n = idx % NC_;
    float acc = 0.f;
    for (int a = lane; a < A_; a += 64)
        acc += attr[b * A_ + a] * class_w[n * A_ + a];
    acc += __shfl_xor(acc, 1);  acc += __shfl_xor(acc, 2);
    acc += __shfl_xor(acc, 4);  acc += __shfl_xor(acc, 8);
    acc += __shfl_xor(acc, 16); acc += __shfl_xor(acc, 32);
    if (lane == 0) out_class[idx] = acc;
}

extern "C" void kernel_launch(void* const* d_in, const int* in_sizes, int n_in,
                              void* d_out, int out_size, void* d_ws, size_t ws_size,
                              hipStream_t stream) {
    (void)in_sizes; (void)n_in; (void)out_size; (void)ws_size;
    const float* l3         = (const float*)d_in[0];
    const float* l4         = (const float*)d_in[1];
    const float* conv_w     = (const float*)d_in[2];
    const float* modulation = (const float*)d_in[3];
    const float* attr_w     = (const float*)d_in[4];
    const float* attr_b     = (const float*)d_in[5];
    const float* class_w    = (const float*)d_in[6];
    float* out = (float*)d_out;
    float* ws  = (float*)d_ws;
    float* asq    = ws + ASQ_OFF;
    float* mf     = ws + MF_OFF;
    float* logits = ws + LOGITS_OFF;
    float* Y      = ws + Y_OFF;
    float* Mp     = ws + MP_OFF;

    zK<<<1104, 256, 0, stream>>>(conv_w, Y, logits, asq);
    kA<<<2592, 256, 0, stream>>>(l3, l4, conv_w, logits, Y);
    kC<<<98, 256, 0, stream>>>(logits, Y, asq, out + MAPS_OFF);
    kD<<<221, 256, 0, stream>>>(out + MAPS_OFF, Mp);
    kE<<<1536, 256, 0, stream>>>(l3, l4, out + MAPS_OFF, Mp, modulation,
                                 out + AF_OFF, mf);
    kF<<<(B_ * A_) / 4, 256, 0, stream>>>(mf, attr_w, attr_b, out + ATTR_OFF);
    kG<<<(B_ * NC_) / 4, 256, 0, stream>>>(out + ATTR_OFF, class_w,
                                           out + CLASS_OFF);
}